// Round 8
// baseline (2244.095 us; speedup 1.0000x reference)
//
#include <hip/hip_runtime.h>
#include <math.h>

// LSTM: L=7, H=49, B=1024, T=512, I=7, O=7. fp32 in/out.
//
// Round 13: finish the latency-decoupling R12 started (+20% confirmed).
//  - R12 post-mortem: cross-step prefetch worked (2472->1993). Step ~9.3k
//    cy; latency-paced loop settles at step ~= latency/cover -> exposed
//    sc1-load latency ~10k cy with cover~1. Three residual exposures:
//    (a) POLLER IN A LOADER WAVE: tid 208 = wave 3 = loader lanes' wave;
//        its poll-loop flag load forces vmcnt waits that DRAIN wave 3's
//        x prefetch every gate. -> pollers move to wave 10 (B-half w7i=3,
//        zero other VM ops; its vmcnt(0) waits only the flag load).
//    (b) DEPTH-2 PREFETCH == latency: deepen to 4 named regs x0r..x3r,
//        unroll x4. C(i) consumes D(i-3)'s load -> cover ~3.2 steps.
//    (c) PRODUCER DRAIN on 1-step-old acks: tbb==2 VMDRAIN covered stores
//        issued one body earlier. -> h history in LDS ring h_sl[16][832];
//        store waves issue block m as ONE 40-store burst at tbb==0, drain
//        at tbb==5 (freshest ack >=5 steps old), publish at tbb==6.
//        Consumer: want = min(((i+2)>>3)+2, 64), initial wait = 2 blocks.
//        Invariants re-verified for depth-4: block-m loads are register-
//        consumed by body 8m+6 -> cons_sig at 8m+7 valid; wrap gate
//        conservative by 1 block; block 63 published by epilogue flag=64.
//  - Everything else from R12 kept: layer pairs in one WG (256x896, 1/CU),
//    LDS intra-pair handoff, 3 ring boundaries, [8][52][16] slots, relaxed
//    agent-scope (sc1) ring+flags, no __syncthreads in loop, fused FC.

constexpr int TT = 512;
constexpr int BB = 1024;
constexpr int HH = 49;
constexpr int GG = 196;

constexpr int RW = 16;                        // ring window (blocks, pow2)
constexpr int SLOT_STEP = 832;                // 52 cols x 16 samps (floats)
constexpr int SLOT_BLK  = 8 * SLOT_STEP;      // 6656 floats per block
constexpr size_t R_GRP       = (size_t)RW * SLOT_BLK;   // per (ring,grp)
constexpr size_t R_LAYER     = 64ull * R_GRP;
constexpr size_t RING_FLOATS = 3ull * R_LAYER;          // rings 1->2,3->4,5->6
constexpr size_t FLAG_INTS   = 6ull * 64 * 32;          // [0..2]prod [3..5]cons
constexpr size_t WS_NEEDED   = RING_FLOATS * 4 + FLAG_INTS * 4;  // ~82 MB

typedef __attribute__((ext_vector_type(8))) short short8;
typedef __attribute__((ext_vector_type(4))) short short4v;
typedef __attribute__((ext_vector_type(4))) float f32x4;

__device__ __forceinline__ float sigmoidf_(float x) {
    return 1.0f / (1.0f + __expf(-x));
}
__device__ __forceinline__ float tanhf_(float x) {
    return 1.0f - 2.0f / (1.0f + __expf(2.0f * x));
}

__device__ __forceinline__ void bf16split(float x, short& hi, short& lo) {
    unsigned u = __float_as_uint(x);
    unsigned r = u + 0x7FFFu + ((u >> 16) & 1u);
    hi = (short)(r >> 16);
    float fhi = __uint_as_float(r & 0xFFFF0000u);
    float rem = x - fhi;
    unsigned u2 = __float_as_uint(rem);
    unsigned r2 = u2 + 0x7FFFu + ((u2 >> 16) & 1u);
    lo = (short)(r2 >> 16);
}

// fragment-order element address (2B units) of A[m][k], m<16, k<128
__device__ __forceinline__ int addr2B(int m, int k) {
    return (k >> 5) * 512 + ((k >> 3) & 3) * 128 + m * 8 + (k & 7);
}

// ring/flag access: relaxed agent-scope atomics (MALL-coherent), no fences
__device__ __forceinline__ float ring_ldf(const float* p) {
    return __hip_atomic_load(p, __ATOMIC_RELAXED, __HIP_MEMORY_SCOPE_AGENT);
}
__device__ __forceinline__ void ring_st(float* p, float v) {
    __hip_atomic_store(p, v, __ATOMIC_RELAXED, __HIP_MEMORY_SCOPE_AGENT);
}
__device__ __forceinline__ int flag_ld(const int* p) {
    return __hip_atomic_load(p, __ATOMIC_RELAXED, __HIP_MEMORY_SCOPE_AGENT);
}
__device__ __forceinline__ void flag_st(int* p, int v) {
    __hip_atomic_store(p, v, __ATOMIC_RELAXED, __HIP_MEMORY_SCOPE_AGENT);
}

#define WGBAR() asm volatile("s_waitcnt lgkmcnt(0)\n\ts_barrier" ::: "memory")
#define VMDRAIN() asm volatile("s_waitcnt vmcnt(0)" ::: "memory")

__global__ void zero_flags(int* f, int n) {
    int i = blockIdx.x * 256 + threadIdx.x;
    if (i < n) f[i] = 0;
}

__global__ __launch_bounds__(896, 1)
void lstm_pair(const float* __restrict__ xin,    // [B,T,7]
               float* __restrict__ ring,         // [3][64][RW][8][52][16]
               int* __restrict__ flags,          // [6][64][32]
               const float* __restrict__ Wih0,   // [196,7]
               const float* __restrict__ Wihr,   // [6,196,49]
               const float* __restrict__ Whh,    // [7,196,49]
               const float* __restrict__ bih,    // [7,196]
               const float* __restrict__ bhh,    // [7,196]
               const float* __restrict__ fcw,    // [7,49]
               const float* __restrict__ fcb,    // [7]
               float* __restrict__ outp)         // [B,T,7]
{
    __shared__ __align__(16) short Ahi[2][2][2048];  // [half][parity][frag]
    __shared__ __align__(16) short Alo[2][2][2048];
    __shared__ __align__(16) float preT[2][13 * 16 * 20];
    __shared__ __align__(16) float h_sl[16][13 * 64]; // B-half h, 16-slot ring
    __shared__ __align__(16) float h_sh[2][16][52];  // layer-6 h, by parity
    __shared__ __align__(16) float w7[7][52];        // fc weights (padded 0)
    __shared__ float bsh[8];

    const int tid  = threadIdx.x;
    const int wave = tid >> 6;                   // 0..13
    const int half = wave >= 7;                  // 0: even layer, 1: odd
    const int w7i  = wave - (half ? 7 : 0);      // wave-within-half 0..6
    const int lane = tid & 63;
    const int quad = lane >> 4;
    const int lrow = lane & 15;
    const int tloc = tid - 448;                  // B-half local tid

    // pollers on wave 10 (B-half w7i=3: zero other VM ops -> its poll
    // vmcnt waits touch nothing else). signaler tid 256 (wave 4, A-half
    // non-loader). publisher tid 704 (wave 11, store wave, post-drain).
    const bool pollB1 = (tid == 640);
    const bool pollH  = (tid == 641);

    const int cls = blockIdx.x >> 6;             // 0..3
    const int grp = blockIdx.x & 63;
    const int b0  = grp << 4;

    const int  lay   = half ? (2 * cls + 1) : (2 * cls);
    const bool laok  = !half || (cls < 3);       // layer exists (lay<=6)
    const int  layc  = laok ? lay : 0;
    const int  DIN   = (layc == 0) ? 7 : 49;
    const int  KSRT  = (layc == 0) ? 2 : 4;
    const float* Wih = (layc == 0) ? Wih0 : (Wihr + (size_t)(layc - 1) * GG * HH);
    const float* Whl = Whh + (size_t)layc * GG * HH;
    const float* bi  = bih + (size_t)layc * GG;
    const float* bh  = bhh + (size_t)layc * GG;

    // ring roles: producer = B-half of cls 0..2 (ring cls); consumer = A-half
    // of cls 1..3 (ring cls-1)
    const int rc_out = cls;                      // producer ring idx
    const int rc_in  = cls - 1;                  // consumer ring idx
    float* rout_g = ring + (size_t)(cls < 3 ? rc_out : 0) * R_LAYER
                         + (size_t)grp * R_GRP;
    const float* rin_g = ring + (size_t)(cls > 0 ? rc_in : 0) * R_LAYER
                              + (size_t)grp * R_GRP;
    int* flag_out  = flags + (size_t)((cls < 3 ? rc_out : 0) * 64 + grp) * 32;
    int* cons_poll = flags + (size_t)((3 + (cls < 3 ? rc_out : 0)) * 64 + grp) * 32;
    int* flag_in   = flags + (size_t)((cls > 0 ? rc_in : 0) * 64 + grp) * 32;
    int* cons_sig  = flags + (size_t)((3 + (cls > 0 ? rc_in : 0)) * 64 + grp) * 32;

    const int ntiles = (w7i < 6) ? 2 : 1;
    const int tA = (w7i < 6) ? w7i : 12;
    const int tB = w7i + 6;

    // ---- B fragments (hi/lo) + bias in VGPRs -----------------------------
    short8 BH[2][4], BL[2][4];
    float  biasv[2];
    #pragma unroll
    for (int ti = 0; ti < 2; ++ti) {
        const int  nt    = ti ? tB : tA;
        const bool valid = laok && (ti < ntiles) && (nt < 13);
        const int  np    = nt * 16 + lrow;
        const int  j     = np >> 2;
        const int  g     = np & 3;
        const bool jb    = valid && (j < HH);
        biasv[ti] = jb ? (bi[g * HH + j] + bh[g * HH + j]) : 0.0f;
        #pragma unroll
        for (int ks = 0; ks < 4; ++ks) {
            #pragma unroll
            for (int jj = 0; jj < 8; ++jj) {
                const int k = ks * 32 + quad * 8 + jj;
                float wv = 0.0f;
                if (jb) {
                    const int r = g * HH + j;
                    if (k < HH)                       wv = Whl[r * HH + k];
                    else if (k >= 52 && k < 52 + DIN) wv = Wih[r * DIN + (k - 52)];
                }
                short h_, l_;
                bf16split(wv, h_, l_);
                BH[ti][ks][jj] = h_;
                BL[ti][ks][jj] = l_;
            }
        }
    }

    // ---- EW cell mapping --------------------------------------------------
    const int  j0 = 4 * tA + quad;               // <=51 (pads compute 0)
    const int  j1 = 4 * tB + quad;
    const bool v1 = (w7i < 6);
    const int  ah0 = addr2B(lrow, j0);
    const int  ah1 = addr2B(lrow, j1);
    const int  bx0 = addr2B(lrow, 52 + j0);      // B-plane x-region target
    const int  bx1 = addr2B(lrow, 52 + j1);
    float cc0 = 0.0f, cc1 = 0.0f;

    // ---- store-wave role (B-half, cls<3): burst block m at tbb==0 --------
    const bool is_stw = half && (cls < 3) && (w7i >= 4);
    const int  st_t0  = (w7i - 4) * 4;
    const int  st_ntt = (w7i == 6) ? 5 : 4;

    // ---- A-half loader role ----------------------------------------------
    bool is_ld = false;
    int  a_st = 0;
    const float* gb = xin;
    if (!half) {
        if (cls == 0) {
            is_ld = (tid < 112);                 // 16 samples x 7 cols
            const int m  = tid / 7;
            const int kx = tid - m * 7;
            a_st = addr2B(m & 15, 52 + kx);
            gb   = xin + ((size_t)(b0 + (m & 15)) * TT) * 7 + kx;
        } else {
            is_ld = (tid < 208);                 // 13 col-quads x 16 samps
            const int jc   = tid >> 4;
            const int samp = tid & 15;
            a_st = addr2B(samp, 52 + 4 * jc);
            gb   = rin_g + (size_t)(4 * jc) * 16 + samp;
        }
    }

    // ---- init ------------------------------------------------------------
    for (int i = tid; i < 4096; i += 896) {      // 2 halves x 2 par x 2048
        ((unsigned*)Ahi)[i] = 0u;
        ((unsigned*)Alo)[i] = 0u;
    }
    if (cls == 3) {
        for (int i = tid; i < 2 * 16 * 52; i += 896) ((float*)h_sh)[i] = 0.0f;
        for (int i = tid; i < 7 * 52; i += 896) {
            const int o = i / 52, k = i - o * 52;
            w7[o][k] = (k < HH) ? fcw[o * HH + k] : 0.0f;
        }
        if (tid < 7) bsh[tid] = fcb[tid];
    }
    __syncthreads();

    if (cls > 0) {                               // need blocks 0,1 before i=6
        if (pollB1) {
            while (flag_ld(flag_in) < 2) __builtin_amdgcn_s_sleep(1);
        }
        WGBAR();
    }

    // prologue (A-half): stage x_0 -> plane[0]; preload x_1..x_3 into
    // x1r..x3r DIRECTLY (no copies; waits land at their C phases).
    float4 x0r = {0,0,0,0}, x1r = {0,0,0,0}, x2r = {0,0,0,0}, x3r = {0,0,0,0};
    if (is_ld) {
        if (cls == 0) {
            short h_, l_;
            bf16split(gb[0], h_, l_);
            Ahi[0][0][a_st] = h_; Alo[0][0][a_st] = l_;
            x1r.x = gb[7]; x2r.x = gb[14]; x3r.x = gb[21];
        } else {
            float4 x0;
            x0.x = ring_ldf(gb);      x0.y = ring_ldf(gb + 16);
            x0.z = ring_ldf(gb + 32); x0.w = ring_ldf(gb + 48);
            #define LD4(dst, off) \
                dst.x = ring_ldf(gb + (off));      dst.y = ring_ldf(gb + (off) + 16); \
                dst.z = ring_ldf(gb + (off) + 32); dst.w = ring_ldf(gb + (off) + 48);
            LD4(x1r, SLOT_STEP)
            LD4(x2r, 2 * SLOT_STEP)
            LD4(x3r, 3 * SLOT_STEP)
            short h0,l0_,h1,l1_,h2,l2_,h3,l3_;
            bf16split(x0.x,h0,l0_); bf16split(x0.y,h1,l1_);
            bf16split(x0.z,h2,l2_); bf16split(x0.w,h3,l3_);
            short4v vh = {h0,h1,h2,h3}, vl = {l0_,l1_,l2_,l3_};
            *(short4v*)&Ahi[0][0][a_st] = vh;
            *(short4v*)&Alo[0][0][a_st] = vl;
        }
    }
    __syncthreads();

    // ---- one pipeline iteration: A does step i, B does step i-1 ----------
    // xUse holds x_{i+1} (loaded 3 bodies earlier); xFill receives x_{i+4}.
    auto body = [&](int i, float4& xUse, float4& xFill) {
        const int pa  = i & 1;
        const int tba = i & 7;
        const int t_b = i - 1;
        const int tbb = t_b & 7;
        const bool aAct = (i < TT);
        const bool bAct = half && (cls < 3) && (i >= 1);

        // producer chores (B-half of cls 0..2)
        if (bAct) {
            // burst-store block m = (t_b>>3)-1 (h_sl slots (8m..8m+7)&15)
            if (is_stw && tbb == 0 && t_b >= 8) {
                const int m    = (t_b >> 3) - 1;
                const int offb = (m & (RW - 1)) * SLOT_BLK;
                const int s0   = (m * 8) & 15;
                #pragma unroll
                for (int s = 0; s < 8; ++s) {
                    const float* hs = h_sl[(s0 + s) & 15];
                    #pragma unroll
                    for (int q = 0; q < 5; ++q) {
                        if (q < st_ntt) {
                            const int tt = st_t0 + q;
                            ring_st(rout_g + offb + s * SLOT_STEP + tt * 64 + lane,
                                    hs[tt * 64 + lane]);
                        }
                    }
                }
            }
            // drain 5 bodies after the burst (freshest ack >= 5 steps old)
            if (tbb == 5 && t_b >= 13) VMDRAIN();
            // publish block m (flag = m+1 = t_b>>3), 1 body after drain;
            // the intervening WGBAR ordered all store waves' drains.
            if (tbb == 6 && (t_b >> 3) >= 1 && tid == 704)
                flag_st(flag_out, t_b >> 3);
        }

        // consumer B1 gate (WG-uniform condition)
        if (cls > 0 && tba == 6 && (i + 2) < TT) {
            if (pollB1) {
                int want = ((i + 2) >> 3) + 2;   // depth-4: covers D(i..i+7)
                if (want > 64) want = 64;
                while (flag_ld(flag_in) < want) __builtin_amdgcn_s_sleep(1);
            }
            WGBAR();
        }
        // consumer B2 signal: block i>>3 loads all register-consumed by C
        // of step 8m+6; barrier-ordered before this body.
        if (cls > 0 && i < TT && tba == 7 && tid == 256)
            flag_st(cons_sig, (i >> 3) + 1);

        if (!half && aAct) {
            // ---- A-half: step t = i --------------------------------------
            // D: issue load of x(t+4) DIRECTLY into xFill (no copy)
            const bool ldnow = is_ld && (i + 4) < TT;
            if (ldnow) {
                if (cls == 0) {
                    xFill.x = gb[(size_t)(i + 4) * 7];
                } else {
                    const int offn = (((i + 4) >> 3) & (RW - 1)) * SLOT_BLK
                                   + ((i + 4) & 7) * SLOT_STEP;
                    xFill.x = ring_ldf(gb + offn);
                    xFill.y = ring_ldf(gb + offn + 16);
                    xFill.z = ring_ldf(gb + offn + 32);
                    xFill.w = ring_ldf(gb + offn + 48);
                }
            }

            // E: MFMA
            short8 AH[4], AL[4];
            #pragma unroll
            for (int ks = 0; ks < 4; ++ks) {
                if (ks < KSRT) {
                    AH[ks] = *(const short8*)&Ahi[0][pa][ks * 512 + lane * 8];
                    AL[ks] = *(const short8*)&Alo[0][pa][ks * 512 + lane * 8];
                }
            }
            f32x4 C0 = {biasv[0], biasv[0], biasv[0], biasv[0]};
            #pragma unroll
            for (int ks = 0; ks < 4; ++ks) {
                if (ks < KSRT) {
                    C0 = __builtin_amdgcn_mfma_f32_16x16x32_bf16(AH[ks], BH[0][ks], C0, 0, 0, 0);
                    C0 = __builtin_amdgcn_mfma_f32_16x16x32_bf16(AL[ks], BH[0][ks], C0, 0, 0, 0);
                    C0 = __builtin_amdgcn_mfma_f32_16x16x32_bf16(AH[ks], BL[0][ks], C0, 0, 0, 0);
                }
            }
            #pragma unroll
            for (int r = 0; r < 4; ++r)
                preT[0][(tA * 16 + 4 * quad + r) * 20 + lrow] = C0[r];
            if (w7i < 6) {
                f32x4 C1 = {biasv[1], biasv[1], biasv[1], biasv[1]};
                #pragma unroll
                for (int ks = 0; ks < 4; ++ks) {
                    if (ks < KSRT) {
                        C1 = __builtin_amdgcn_mfma_f32_16x16x32_bf16(AH[ks], BH[1][ks], C1, 0, 0, 0);
                        C1 = __builtin_amdgcn_mfma_f32_16x16x32_bf16(AL[ks], BH[1][ks], C1, 0, 0, 0);
                        C1 = __builtin_amdgcn_mfma_f32_16x16x32_bf16(AH[ks], BL[1][ks], C1, 0, 0, 0);
                    }
                }
                #pragma unroll
                for (int r = 0; r < 4; ++r)
                    preT[0][(tB * 16 + 4 * quad + r) * 20 + lrow] = C1[r];
            }

            // G: EW -> own h plane + (B x-region | h_sh)
            {
                const f32x4 gt = *(const f32x4*)&preT[0][(tA * 16 + lrow) * 20 + 4 * quad];
                const float i_ = sigmoidf_(gt.x);
                const float f_ = sigmoidf_(gt.y);
                const float g_ = tanhf_(gt.z);
                const float o_ = sigmoidf_(gt.w);
                cc0 = f_ * cc0 + i_ * g_;
                const float hv = o_ * tanhf_(cc0);
                short hh, hl;
                bf16split(hv, hh, hl);
                Ahi[0][pa ^ 1][ah0] = hh;
                Alo[0][pa ^ 1][ah0] = hl;
                if (cls < 3) {
                    Ahi[1][pa ^ 1][bx0] = hh;
                    Alo[1][pa ^ 1][bx0] = hl;
                } else {
                    h_sh[pa ^ 1][lrow][j0] = hv;
                }
            }
            if (v1) {
                const f32x4 gt = *(const f32x4*)&preT[0][(tB * 16 + lrow) * 20 + 4 * quad];
                const float i_ = sigmoidf_(gt.x);
                const float f_ = sigmoidf_(gt.y);
                const float g_ = tanhf_(gt.z);
                const float o_ = sigmoidf_(gt.w);
                cc1 = f_ * cc1 + i_ * g_;
                const float hv = o_ * tanhf_(cc1);
                short hh, hl;
                bf16split(hv, hh, hl);
                Ahi[0][pa ^ 1][ah1] = hh;
                Alo[0][pa ^ 1][ah1] = hl;
                if (cls < 3) {
                    Ahi[1][pa ^ 1][bx1] = hh;
                    Alo[1][pa ^ 1][bx1] = hl;
                } else {
                    h_sh[pa ^ 1][lrow][j1] = hv;
                }
            }

            // C: stage x(t+1) from xUse (loaded 3 bodies earlier)
            if (is_ld && (i + 1) < TT) {
                if (cls == 0) {
                    short h_, l_;
                    bf16split(xUse.x, h_, l_);
                    Ahi[0][pa ^ 1][a_st] = h_; Alo[0][pa ^ 1][a_st] = l_;
                } else {
                    short h0,l0_,h1,l1_,h2,l2_,h3,l3_;
                    bf16split(xUse.x,h0,l0_); bf16split(xUse.y,h1,l1_);
                    bf16split(xUse.z,h2,l2_); bf16split(xUse.w,h3,l3_);
                    short4v vh = {h0,h1,h2,h3}, vl = {l0_,l1_,l2_,l3_};
                    *(short4v*)&Ahi[0][pa ^ 1][a_st] = vh;
                    *(short4v*)&Alo[0][pa ^ 1][a_st] = vl;
                }
            }
        } else if (bAct) {
            // ---- B-half: step t_b = i-1 ----------------------------------
            short8 AH[4], AL[4];
            #pragma unroll
            for (int ks = 0; ks < 4; ++ks) {
                AH[ks] = *(const short8*)&Ahi[1][pa][ks * 512 + lane * 8];
                AL[ks] = *(const short8*)&Alo[1][pa][ks * 512 + lane * 8];
            }
            f32x4 C0 = {biasv[0], biasv[0], biasv[0], biasv[0]};
            #pragma unroll
            for (int ks = 0; ks < 4; ++ks) {
                C0 = __builtin_amdgcn_mfma_f32_16x16x32_bf16(AH[ks], BH[0][ks], C0, 0, 0, 0);
                C0 = __builtin_amdgcn_mfma_f32_16x16x32_bf16(AL[ks], BH[0][ks], C0, 0, 0, 0);
                C0 = __builtin_amdgcn_mfma_f32_16x16x32_bf16(AH[ks], BL[0][ks], C0, 0, 0, 0);
            }
            #pragma unroll
            for (int r = 0; r < 4; ++r)
                preT[1][(tA * 16 + 4 * quad + r) * 20 + lrow] = C0[r];
            if (w7i < 6) {
                f32x4 C1 = {biasv[1], biasv[1], biasv[1], biasv[1]};
                #pragma unroll
                for (int ks = 0; ks < 4; ++ks) {
                    C1 = __builtin_amdgcn_mfma_f32_16x16x32_bf16(AH[ks], BH[1][ks], C1, 0, 0, 0);
                    C1 = __builtin_amdgcn_mfma_f32_16x16x32_bf16(AL[ks], BH[1][ks], C1, 0, 0, 0);
                    C1 = __builtin_amdgcn_mfma_f32_16x16x32_bf16(AH[ks], BL[1][ks], C1, 0, 0, 0);
                }
                #pragma unroll
                for (int r = 0; r < 4; ++r)
                    preT[1][(tB * 16 + 4 * quad + r) * 20 + lrow] = C1[r];
            }

            // EW -> own h plane + h_sl slot t_b&15 (ring payload in fp32)
            {
                const f32x4 gt = *(const f32x4*)&preT[1][(tA * 16 + lrow) * 20 + 4 * quad];
                const float i_ = sigmoidf_(gt.x);
                const float f_ = sigmoidf_(gt.y);
                const float g_ = tanhf_(gt.z);
                const float o_ = sigmoidf_(gt.w);
                cc0 = f_ * cc0 + i_ * g_;
                const float hv = o_ * tanhf_(cc0);
                short hh, hl;
                bf16split(hv, hh, hl);
                Ahi[1][pa ^ 1][ah0] = hh;
                Alo[1][pa ^ 1][ah0] = hl;
                h_sl[t_b & 15][tA * 64 + lane] = hv;
            }
            if (v1) {
                const f32x4 gt = *(const f32x4*)&preT[1][(tB * 16 + lrow) * 20 + 4 * quad];
                const float i_ = sigmoidf_(gt.x);
                const float f_ = sigmoidf_(gt.y);
                const float g_ = tanhf_(gt.z);
                const float o_ = sigmoidf_(gt.w);
                cc1 = f_ * cc1 + i_ * g_;
                const float hv = o_ * tanhf_(cc1);
                short hh, hl;
                bf16split(hv, hh, hl);
                Ahi[1][pa ^ 1][ah1] = hh;
                Alo[1][pa ^ 1][ah1] = hl;
                h_sl[t_b & 15][tB * 64 + lane] = hv;
            }
        }

        // FC (class 3, B-half lanes): out(t = i-1) from h_sh[pa]
        if (cls == 3 && half && tloc < 112 && i >= 1) {
            const int s = tloc / 7;
            const int o = tloc - s * 7;
            const float* hr = h_sh[pa][s];
            float acc = bsh[o];
            #pragma unroll
            for (int k = 0; k < 52; k += 4) {
                const f32x4 hv4 = *(const f32x4*)&hr[k];
                const f32x4 wv4 = *(const f32x4*)&w7[o][k];
                acc = fmaf(hv4.x, wv4.x, acc);
                acc = fmaf(hv4.y, wv4.y, acc);
                acc = fmaf(hv4.z, wv4.z, acc);
                acc = fmaf(hv4.w, wv4.w, acc);
            }
            outp[((size_t)(b0 + s) * TT + (i - 1)) * 7 + o] = acc;
        }

        // H: producer wrap gate — burst of block i>>3-1.. conservative by
        // one block; need cons >= (i>>3)-RW+1 before this 8-step window.
        if (cls < 3 && (i & 7) == 0 && i >= RW * 8 && i < TT && pollH) {
            const int need = (i >> 3) - RW + 1;
            while (flag_ld(cons_poll) < need) __builtin_amdgcn_s_sleep(1);
        }

        WGBAR();   // lgkm-only; vm loads/stores stay in flight
    };

    // ---- iteration loop: unroll x4 (reg r holds x values == r mod 4) -----
    for (int ii = 0; ii < TT; ii += 4) {
        body(ii,     x1r, x0r);
        body(ii + 1, x2r, x1r);
        body(ii + 2, x3r, x2r);
        body(ii + 3, x0r, x3r);
    }
    body(TT, x1r, x0r);          // trailing B-half drain iteration (t_b=511)

    // producer epilogue: burst block 63 (h 504..511, slots 8..15), drain,
    // publish completion flag (=64, covers everything).
    if (is_stw) {
        const int offb = (63 & (RW - 1)) * SLOT_BLK;
        #pragma unroll
        for (int s = 0; s < 8; ++s) {
            const float* hs = h_sl[(504 + s) & 15];
            #pragma unroll
            for (int q = 0; q < 5; ++q) {
                if (q < st_ntt) {
                    const int tt = st_t0 + q;
                    ring_st(rout_g + offb + s * SLOT_STEP + tt * 64 + lane,
                            hs[tt * 64 + lane]);
                }
            }
        }
    }
    if (cls < 3) {
        VMDRAIN();
        __syncthreads();
        if (tid == 704)
            flag_st(flag_out, 64);
    }
}

// ======================= fallback path (R4, per-layer) ======================

template<int DIN>
__global__ __launch_bounds__(448)
void lstm_fb(const float* xin, float* hout,
             const float* __restrict__ Wih, const float* __restrict__ Whh,
             const float* __restrict__ bihp, const float* __restrict__ bhhp)
{
    constexpr int XO = 52;
    constexpr int KTOT = XO + DIN;
    constexpr int KSTEPS = (KTOT + 31) / 32;
    __shared__ short Ahi[2][KSTEPS * 512];
    __shared__ short Alo[2][KSTEPS * 512];
    __shared__ float preT[13 * 64];

    const int tid = threadIdx.x, wave = tid >> 6, lane = tid & 63;
    const int quad = lane >> 4, lrow = lane & 15;
    const int b0 = blockIdx.x * 4;
    const int ntiles = (wave < 6) ? 2 : 1;
    const int tileA = (wave < 6) ? wave : 12;
    const int tileB = wave + 6;

    short8 BH[2][KSTEPS], BL[2][KSTEPS];
    float biasv[2];
    #pragma unroll
    for (int ti = 0; ti < 2; ++ti) {
        const int nt = ti ? tileB : tileA;
        const bool valid = (ti < ntiles);
        const int np = nt * 16 + lrow, j = np >> 2, g = np & 3;
        biasv[ti] = (valid && j < HH) ? (bihp[g*HH+j] + bhhp[g*HH+j]) : 0.0f;
        #pragma unroll
        for (int ks = 0; ks < KSTEPS; ++ks)
            #pragma unroll
            for (int jj = 0; jj < 8; ++jj) {
                const int k = ks * 32 + quad * 8 + jj;
                float wv = 0.0f;
                if (valid && j < HH) {
                    const int r = g * HH + j;
                    if (k < HH) wv = Whh[r * HH + k];
                    else if (k >= XO && k < KTOT) wv = Wih[r * DIN + (k - XO)];
                }
                short h_, l_; bf16split(wv, h_, l_);
                BH[ti][ks][jj] = h_; BL[ti][ks][jj] = l_;
            }
    }

    const int ec = lane & 15, ew_jj = ec >> 2, ew_m = ec & 3, ew_ti = lane >> 4;
    const bool is_ew = (lane < 32) && (ew_ti < ntiles);
    const int ew_nt = ew_ti ? tileB : tileA;
    const int ew_j = 4 * ew_nt + ew_jj;
    const bool ew_ok = is_ew && (ew_j < HH);
    const int pa0 = (ew_nt*16 + 4*ew_jj + 0)*4 + ew_m;
    const int pa1 = (ew_nt*16 + 4*ew_jj + 1)*4 + ew_m;
    const int pa2 = (ew_nt*16 + 4*ew_jj + 2)*4 + ew_m;
    const int pa3 = (ew_nt*16 + 4*ew_jj + 3)*4 + ew_m;
    const int ew_ah = addr2B(ew_m, ew_j);
    float cc = 0.0f;

    const int lx = tid;
    const bool is_loader = (lx < 4 * DIN);
    const int ld_m = is_loader ? (lx & 3) : 0, ld_k = is_loader ? (lx >> 2) : 0;
    const int xaddr = addr2B(ld_m, XO + ld_k);
    const size_t xbase = ((size_t)(b0 + ld_m) * TT) * DIN + ld_k;
    float* houtp = hout + ((size_t)(b0 + ew_m) * TT) * HH + (ew_ok ? ew_j : 0);

    for (int i = tid; i < KSTEPS * 512; i += 448) {
        ((unsigned*)Ahi)[i] = 0u; ((unsigned*)Alo)[i] = 0u;
    }
    __syncthreads();
    if (is_loader) {
        short h_, l_; bf16split(xin[xbase], h_, l_);
        Ahi[0][xaddr] = h_; Alo[0][xaddr] = l_;
    }
    __syncthreads();

    for (int t = 0; t < TT; ++t) {
        const int p = t & 1;
        float xnext = 0.0f;
        if (is_loader && (t + 1 < TT)) xnext = xin[xbase + (size_t)(t+1) * DIN];

        short8 AH[KSTEPS], AL[KSTEPS];
        #pragma unroll
        for (int ks = 0; ks < KSTEPS; ++ks) {
            AH[ks] = *(const short8*)&Ahi[p][ks * 512 + lane * 8];
            AL[ks] = *(const short8*)&Alo[p][ks * 512 + lane * 8];
        }
        #pragma unroll
        for (int ti = 0; ti < 2; ++ti) {
            f32x4 C = {biasv[ti], biasv[ti], biasv[ti], biasv[ti]};
            #pragma unroll
            for (int ks = 0; ks < KSTEPS; ++ks) {
                C = __builtin_amdgcn_mfma_f32_16x16x32_bf16(AH[ks], BH[ti][ks], C, 0, 0, 0);
                C = __builtin_amdgcn_mfma_f32_16x16x32_bf16(AL[ks], BH[ti][ks], C, 0, 0, 0);
                C = __builtin_amdgcn_mfma_f32_16x16x32_bf16(AH[ks], BL[ti][ks], C, 0, 0, 0);
            }
            if (ti < ntiles && lane < 16) {
                const int nt = ti ? tileB : tileA;
                *(f32x4*)&preT[(nt * 16 + lrow) * 4] = C;
            }
        }
        if (is_ew) {
            const float i_ = sigmoidf_(preT[pa0]);
            const float f_ = sigmoidf_(preT[pa1]);
            const float g_ = tanhf_(preT[pa2]);
            const float o_ = sigmoidf_(preT[pa3]);
            cc = f_ * cc + i_ * g_;
            const float hv = o_ * tanhf_(cc);
            if (ew_ok) {
                short hh, hl; bf16split(hv, hh, hl);
                Ahi[p ^ 1][ew_ah] = hh; Alo[p ^ 1][ew_ah] = hl;
                houtp[(size_t)t * HH] = hv;
            }
        }
        if (is_loader && (t + 1 < TT)) {
            short h_, l_; bf16split(xnext, h_, l_);
            Ahi[p ^ 1][xaddr] = h_; Alo[p ^ 1][xaddr] = l_;
        }
        __syncthreads();
    }
}

__global__ __launch_bounds__(256)
void fc_fb(const float* __restrict__ hbuf, const float* __restrict__ fcw,
           const float* __restrict__ fcb, float* __restrict__ outp)
{
    constexpr int HP = 52;
    __shared__ float w[7][HP];
    __shared__ float bsh[8];
    const int tid = threadIdx.x;
    for (int i = tid; i < 7 * HP; i += 256) {
        const int o = i / HP, k = i - o * HP;
        w[o][k] = (k < HH) ? fcw[o * HH + k] : 0.0f;
    }
    if (tid < 7) bsh[tid] = fcb[tid];
    __syncthreads();
    const size_t i = (size_t)blockIdx.x * 256 + tid;
    float acc[7];
    #pragma unroll
    for (int j = 0; j < 7; ++j) acc[j] = bsh[j];
    const float* hp = hbuf + i * HH;
    #pragma unroll
    for (int k = 0; k < HH; ++k) {
        const float hv = hp[k];
        #pragma unroll
        for (int j = 0; j < 7; ++j) acc[j] = fmaf(hv, w[j][k], acc[j]);
    }
    #pragma unroll
    for (int j = 0; j < 7; ++j) outp[i * 7 + j] = acc[j];
}

extern "C" void kernel_launch(void* const* d_in, const int* in_sizes, int n_in,
                              void* d_out, int out_size, void* d_ws, size_t ws_size,
                              hipStream_t stream)
{
    const float* x    = (const float*)d_in[0];
    const float* Wih0 = (const float*)d_in[1];
    const float* Wihr = (const float*)d_in[2];
    const float* Whh  = (const float*)d_in[3];
    const float* bih  = (const float*)d_in[4];
    const float* bhh  = (const float*)d_in[5];
    const float* fcw  = (const float*)d_in[6];
    const float* fcb  = (const float*)d_in[7];
    float* outp = (float*)d_out;

    if (ws_size >= WS_NEEDED) {
        float* ring  = (float*)d_ws;
        int*   flags = (int*)((char*)d_ws + RING_FLOATS * 4);
        zero_flags<<<(int)((FLAG_INTS + 255) / 256), 256, 0, stream>>>(
            flags, (int)FLAG_INTS);
        lstm_pair<<<256, 896, 0, stream>>>(x, ring, flags, Wih0, Wihr,
                                           Whh, bih, bhh, fcw, fcb, outp);
    } else {
        float* hbuf = (float*)d_ws;   // [B,T,49]
        lstm_fb<7><<<BB / 4, 448, 0, stream>>>(x, hbuf, Wih0, Whh, bih, bhh);
        for (int l = 1; l < 7; ++l) {
            lstm_fb<49><<<BB / 4, 448, 0, stream>>>(
                hbuf, hbuf,
                Wihr + (size_t)(l - 1) * GG * HH,
                Whh  + (size_t)l * GG * HH,
                bih  + (size_t)l * GG,
                bhh  + (size_t)l * GG);
        }
        fc_fb<<<(BB * TT) / 256, 256, 0, stream>>>(hbuf, fcw, fcb, outp);
    }
}

// Round 9
// 1940.639 us; speedup vs baseline: 1.1564x; 1.1564x over previous
//
#include <hip/hip_runtime.h>
#include <math.h>

// LSTM: L=7, H=49, B=1024, T=512, I=7, O=7. fp32 in/out.
//
// Round 14: revert to R12 structure + packed-bf16 ring payload + poller fix.
//  - R13 post-mortem: steady body time UNCHANGED by depth-4 prefetch
//    (3.76 -> 3.89 us incl. longer fill) -> load-latency pacing theory dead
//    beyond depth 2; the regression was pipeline fill (+25 bodies/boundary)
//    and a 42 ms outlier dispatch (burst/publish protocol intermittently
//    near-livelocked) disqualifies R13's producer protocol.
//  - R14 = R12 (proven 1993 us, clean dispatches) + two safe deltas:
//    (1) PACKED RING PAYLOAD: producer EW already has h's bf16 (hi,lo) in
//        regs -> ring carries u32 (hi<<16|lo). Consumer unpacks (2 ops/val)
//        instead of re-running bf16split (~9 ops/val) on 4 vals/lane/body.
//        Identical staged values -> absmax unchanged. Cuts the highest
//        counter (VALUBusy 29%) and shrinks body code.
//    (2) pollers on wave 10 (tids 640/641, B-half w7i=3, zero other VM ops)
//        so poll waits never drain a loader wave's prefetch queue.
//  - Everything else R12-verbatim: layer pairs in one WG (256x896, 1/CU),
//    depth-2 named-reg prefetch (xO/xE, unroll x2, no rotate copy), LDS
//    intra-pair handoff, 3 ring boundaries, [8][52][16] slots, RW=16,
//    relaxed agent-scope (sc1) ring+flags, per-body spread stores, fused FC.

constexpr int TT = 512;
constexpr int BB = 1024;
constexpr int HH = 49;
constexpr int GG = 196;

constexpr int RW = 16;                        // ring window (blocks, pow2)
constexpr int SLOT_STEP = 832;                // 52 cols x 16 samps (floats)
constexpr int SLOT_BLK  = 8 * SLOT_STEP;      // 6656 floats per block
constexpr size_t R_GRP       = (size_t)RW * SLOT_BLK;   // per (ring,grp)
constexpr size_t R_LAYER     = 64ull * R_GRP;
constexpr size_t RING_FLOATS = 3ull * R_LAYER;          // rings 1->2,3->4,5->6
constexpr size_t FLAG_INTS   = 6ull * 64 * 32;          // [0..2]prod [3..5]cons
constexpr size_t WS_NEEDED   = RING_FLOATS * 4 + FLAG_INTS * 4;  // ~82 MB

typedef __attribute__((ext_vector_type(8))) short short8;
typedef __attribute__((ext_vector_type(4))) short short4v;
typedef __attribute__((ext_vector_type(4))) float f32x4;

__device__ __forceinline__ float sigmoidf_(float x) {
    return 1.0f / (1.0f + __expf(-x));
}
__device__ __forceinline__ float tanhf_(float x) {
    return 1.0f - 2.0f / (1.0f + __expf(2.0f * x));
}

__device__ __forceinline__ void bf16split(float x, short& hi, short& lo) {
    unsigned u = __float_as_uint(x);
    unsigned r = u + 0x7FFFu + ((u >> 16) & 1u);
    hi = (short)(r >> 16);
    float fhi = __uint_as_float(r & 0xFFFF0000u);
    float rem = x - fhi;
    unsigned u2 = __float_as_uint(rem);
    unsigned r2 = u2 + 0x7FFFu + ((u2 >> 16) & 1u);
    lo = (short)(r2 >> 16);
}

// fragment-order element address (2B units) of A[m][k], m<16, k<128
__device__ __forceinline__ int addr2B(int m, int k) {
    return (k >> 5) * 512 + ((k >> 3) & 3) * 128 + m * 8 + (k & 7);
}

// ring/flag access: relaxed agent-scope atomics (MALL-coherent), no fences
__device__ __forceinline__ float ring_ldf(const float* p) {
    return __hip_atomic_load(p, __ATOMIC_RELAXED, __HIP_MEMORY_SCOPE_AGENT);
}
__device__ __forceinline__ void ring_st(float* p, float v) {
    __hip_atomic_store(p, v, __ATOMIC_RELAXED, __HIP_MEMORY_SCOPE_AGENT);
}
__device__ __forceinline__ int flag_ld(const int* p) {
    return __hip_atomic_load(p, __ATOMIC_RELAXED, __HIP_MEMORY_SCOPE_AGENT);
}
__device__ __forceinline__ void flag_st(int* p, int v) {
    __hip_atomic_store(p, v, __ATOMIC_RELAXED, __HIP_MEMORY_SCOPE_AGENT);
}

// packed bf16 pair helpers (hi in top 16 bits)
__device__ __forceinline__ float pack_hl(short hi, short lo) {
    return __uint_as_float(((unsigned)(unsigned short)hi << 16)
                           | (unsigned)(unsigned short)lo);
}
__device__ __forceinline__ void unpack_hl(float f, short& hi, short& lo) {
    const unsigned u = __float_as_uint(f);
    hi = (short)(u >> 16);
    lo = (short)(u & 0xFFFFu);
}

#define WGBAR() asm volatile("s_waitcnt lgkmcnt(0)\n\ts_barrier" ::: "memory")
#define VMDRAIN() asm volatile("s_waitcnt vmcnt(0)" ::: "memory")

__global__ void zero_flags(int* f, int n) {
    int i = blockIdx.x * 256 + threadIdx.x;
    if (i < n) f[i] = 0;
}

__global__ __launch_bounds__(896, 1)
void lstm_pair(const float* __restrict__ xin,    // [B,T,7]
               float* __restrict__ ring,         // [3][64][RW][8][52][16] packed
               int* __restrict__ flags,          // [6][64][32]
               const float* __restrict__ Wih0,   // [196,7]
               const float* __restrict__ Wihr,   // [6,196,49]
               const float* __restrict__ Whh,    // [7,196,49]
               const float* __restrict__ bih,    // [7,196]
               const float* __restrict__ bhh,    // [7,196]
               const float* __restrict__ fcw,    // [7,49]
               const float* __restrict__ fcb,    // [7]
               float* __restrict__ outp)         // [B,T,7]
{
    __shared__ __align__(16) short Ahi[2][2][2048];  // [half][parity][frag]
    __shared__ __align__(16) short Alo[2][2][2048];
    __shared__ __align__(16) float preT[2][13 * 16 * 20];
    __shared__ __align__(16) float h_st[2][13 * 64]; // B-half h PACKED, dbuf
    __shared__ __align__(16) float h_sh[2][16][52];  // layer-6 h fp32, parity
    __shared__ __align__(16) float w7[7][52];        // fc weights (padded 0)
    __shared__ float bsh[8];

    const int tid  = threadIdx.x;
    const int wave = tid >> 6;                   // 0..13
    const int half = wave >= 7;                  // 0: even layer, 1: odd
    const int w7i  = wave - (half ? 7 : 0);      // wave-within-half 0..6
    const int lane = tid & 63;
    const int quad = lane >> 4;
    const int lrow = lane & 15;
    const int tloc = tid - 448;                  // B-half local tid

    // pollers on wave 10 (B-half w7i=3: zero other VM ops, so poll waits
    // never drain a prefetch queue). signaler tid 256; publisher tid 704.
    const bool pollB1 = (tid == 640);
    const bool pollH  = (tid == 641);

    const int cls = blockIdx.x >> 6;             // 0..3
    const int grp = blockIdx.x & 63;
    const int b0  = grp << 4;

    const int  lay   = half ? (2 * cls + 1) : (2 * cls);
    const bool laok  = !half || (cls < 3);       // layer exists (lay<=6)
    const int  layc  = laok ? lay : 0;
    const int  DIN   = (layc == 0) ? 7 : 49;
    const int  KSRT  = (layc == 0) ? 2 : 4;
    const float* Wih = (layc == 0) ? Wih0 : (Wihr + (size_t)(layc - 1) * GG * HH);
    const float* Whl = Whh + (size_t)layc * GG * HH;
    const float* bi  = bih + (size_t)layc * GG;
    const float* bh  = bhh + (size_t)layc * GG;

    // ring roles: producer = B-half of cls 0..2 (ring cls); consumer = A-half
    // of cls 1..3 (ring cls-1)
    const int rc_out = cls;                      // producer ring idx
    const int rc_in  = cls - 1;                  // consumer ring idx
    float* rout_g = ring + (size_t)(cls < 3 ? rc_out : 0) * R_LAYER
                         + (size_t)grp * R_GRP;
    const float* rin_g = ring + (size_t)(cls > 0 ? rc_in : 0) * R_LAYER
                              + (size_t)grp * R_GRP;
    int* flag_out  = flags + (size_t)((cls < 3 ? rc_out : 0) * 64 + grp) * 32;
    int* cons_poll = flags + (size_t)((3 + (cls < 3 ? rc_out : 0)) * 64 + grp) * 32;
    int* flag_in   = flags + (size_t)((cls > 0 ? rc_in : 0) * 64 + grp) * 32;
    int* cons_sig  = flags + (size_t)((3 + (cls > 0 ? rc_in : 0)) * 64 + grp) * 32;

    const int ntiles = (w7i < 6) ? 2 : 1;
    const int tA = (w7i < 6) ? w7i : 12;
    const int tB = w7i + 6;

    // ---- B fragments (hi/lo) + bias in VGPRs -----------------------------
    short8 BH[2][4], BL[2][4];
    float  biasv[2];
    #pragma unroll
    for (int ti = 0; ti < 2; ++ti) {
        const int  nt    = ti ? tB : tA;
        const bool valid = laok && (ti < ntiles) && (nt < 13);
        const int  np    = nt * 16 + lrow;
        const int  j     = np >> 2;
        const int  g     = np & 3;
        const bool jb    = valid && (j < HH);
        biasv[ti] = jb ? (bi[g * HH + j] + bh[g * HH + j]) : 0.0f;
        #pragma unroll
        for (int ks = 0; ks < 4; ++ks) {
            #pragma unroll
            for (int jj = 0; jj < 8; ++jj) {
                const int k = ks * 32 + quad * 8 + jj;
                float wv = 0.0f;
                if (jb) {
                    const int r = g * HH + j;
                    if (k < HH)                       wv = Whl[r * HH + k];
                    else if (k >= 52 && k < 52 + DIN) wv = Wih[r * DIN + (k - 52)];
                }
                short h_, l_;
                bf16split(wv, h_, l_);
                BH[ti][ks][jj] = h_;
                BL[ti][ks][jj] = l_;
            }
        }
    }

    // ---- EW cell mapping --------------------------------------------------
    const int  j0 = 4 * tA + quad;               // <=51 (pads compute 0)
    const int  j1 = 4 * tB + quad;
    const bool v1 = (w7i < 6);
    const int  ah0 = addr2B(lrow, j0);
    const int  ah1 = addr2B(lrow, j1);
    const int  bx0 = addr2B(lrow, 52 + j0);      // B-plane x-region target
    const int  bx1 = addr2B(lrow, 52 + j1);
    float cc0 = 0.0f, cc1 = 0.0f;

    // ---- store-wave role (B-half, cls<3): push h(t_b-1) to the ring ------
    const bool is_stw = half && (cls < 3) && (w7i >= 4);
    const int  st_t0  = (w7i - 4) * 4;
    const int  st_ntt = (w7i == 6) ? 5 : 4;

    // ---- A-half loader role ----------------------------------------------
    bool is_ld = false;
    int  a_st = 0;
    const float* gb = xin;
    if (!half) {
        if (cls == 0) {
            is_ld = (tid < 112);                 // 16 samples x 7 cols
            const int m  = tid / 7;
            const int kx = tid - m * 7;
            a_st = addr2B(m & 15, 52 + kx);
            gb   = xin + ((size_t)(b0 + (m & 15)) * TT) * 7 + kx;
        } else {
            is_ld = (tid < 208);                 // 13 col-quads x 16 samps
            const int jc   = tid >> 4;
            const int samp = tid & 15;
            a_st = addr2B(samp, 52 + 4 * jc);
            gb   = rin_g + (size_t)(4 * jc) * 16 + samp;
        }
    }

    // ---- init ------------------------------------------------------------
    for (int i = tid; i < 4096; i += 896) {      // 2 halves x 2 par x 2048
        ((unsigned*)Ahi)[i] = 0u;
        ((unsigned*)Alo)[i] = 0u;
    }
    if (cls == 3) {
        for (int i = tid; i < 2 * 16 * 52; i += 896) ((float*)h_sh)[i] = 0.0f;
        for (int i = tid; i < 7 * 52; i += 896) {
            const int o = i / 52, k = i - o * 52;
            w7[o][k] = (k < HH) ? fcw[o * HH + k] : 0.0f;
        }
        if (tid < 7) bsh[tid] = fcb[tid];
    }
    __syncthreads();

    if (cls > 0) {                               // wait for input block 0
        if (pollB1) {
            while (flag_ld(flag_in) < 1) __builtin_amdgcn_s_sleep(1);
        }
        WGBAR();
    }

    // prologue (A-half): stage x_0 -> plane[0]; x_1 -> xO (used at C(0)).
    float4 xO = {0, 0, 0, 0}, xE = {0, 0, 0, 0};
    if (is_ld) {
        if (cls == 0) {
            short h_, l_;
            bf16split(gb[0], h_, l_);
            Ahi[0][0][a_st] = h_; Alo[0][0][a_st] = l_;
            xO.x = gb[7];
        } else {
            float4 x0;
            x0.x = ring_ldf(gb);      x0.y = ring_ldf(gb + 16);
            x0.z = ring_ldf(gb + 32); x0.w = ring_ldf(gb + 48);
            xO.x = ring_ldf(gb + SLOT_STEP);      xO.y = ring_ldf(gb + SLOT_STEP + 16);
            xO.z = ring_ldf(gb + SLOT_STEP + 32); xO.w = ring_ldf(gb + SLOT_STEP + 48);
            short h0,l0_,h1,l1_,h2,l2_,h3,l3_;
            unpack_hl(x0.x, h0, l0_); unpack_hl(x0.y, h1, l1_);
            unpack_hl(x0.z, h2, l2_); unpack_hl(x0.w, h3, l3_);
            short4v vh = {h0,h1,h2,h3}, vl = {l0_,l1_,l2_,l3_};
            *(short4v*)&Ahi[0][0][a_st] = vh;
            *(short4v*)&Alo[0][0][a_st] = vl;
        }
    }
    __syncthreads();

    // ---- one pipeline iteration: A does step i, B does step i-1 ----------
    // xUse holds x_{i+1} (loaded one body earlier); xFill receives x_{i+2}
    // directly from the load (wait deferred to the NEXT body's C phase).
    auto body = [&](int i, float4& xUse, float4& xFill) {
        const int pa  = i & 1;
        const int tba = i & 7;
        const int t_b = i - 1;
        const int tbb = t_b & 7;
        const int p2  = t_b & 1;
        const bool aAct = (i < TT);
        const bool bAct = half && (cls < 3) && (i >= 1);

        // producer chores (B-half)
        if (bAct) {
            if (tbb == 2) VMDRAIN();
            if (tbb == 3 && (t_b >> 3) >= 1 && tid == 704)
                flag_st(flag_out, t_b >> 3);
            // S: store waves push h(t_b-1) from h_st (packed bits, verbatim)
            if (is_stw && i >= 2) {
                const int tp   = t_b - 1;
                const int offp = ((tp >> 3) & (RW - 1)) * SLOT_BLK
                               + (tp & 7) * SLOT_STEP;
                const float* hs = h_st[p2 ^ 1];
                #pragma unroll
                for (int q = 0; q < 5; ++q) {
                    if (q < st_ntt) {
                        const int tt = st_t0 + q;
                        ring_st(rout_g + offp + tt * 64 + lane, hs[tt * 64 + lane]);
                    }
                }
            }
        }

        // consumer B1 gate (WG-uniform condition)
        if (cls > 0 && tba == 6 && (i + 2) < TT) {
            if (pollB1) {
                const int want = ((i + 2) >> 3) + 1;
                while (flag_ld(flag_in) < want) __builtin_amdgcn_s_sleep(1);
            }
            WGBAR();
        }
        // consumer B2 signal
        if (cls > 0 && i < TT && tba == 7 && tid == 256)
            flag_st(cons_sig, (i >> 3) + 1);

        if (!half && aAct) {
            // ---- A-half: step t = i --------------------------------------
            // D: issue load of x(t+2) DIRECTLY into xFill (no copy)
            const bool ldnow = is_ld && (i + 2) < TT;
            if (ldnow) {
                if (cls == 0) {
                    xFill.x = gb[(size_t)(i + 2) * 7];
                } else {
                    const int offn = (((i + 2) >> 3) & (RW - 1)) * SLOT_BLK
                                   + ((i + 2) & 7) * SLOT_STEP;
                    xFill.x = ring_ldf(gb + offn);
                    xFill.y = ring_ldf(gb + offn + 16);
                    xFill.z = ring_ldf(gb + offn + 32);
                    xFill.w = ring_ldf(gb + offn + 48);
                }
            }

            // E: MFMA
            short8 AH[4], AL[4];
            #pragma unroll
            for (int ks = 0; ks < 4; ++ks) {
                if (ks < KSRT) {
                    AH[ks] = *(const short8*)&Ahi[0][pa][ks * 512 + lane * 8];
                    AL[ks] = *(const short8*)&Alo[0][pa][ks * 512 + lane * 8];
                }
            }
            f32x4 C0 = {biasv[0], biasv[0], biasv[0], biasv[0]};
            #pragma unroll
            for (int ks = 0; ks < 4; ++ks) {
                if (ks < KSRT) {
                    C0 = __builtin_amdgcn_mfma_f32_16x16x32_bf16(AH[ks], BH[0][ks], C0, 0, 0, 0);
                    C0 = __builtin_amdgcn_mfma_f32_16x16x32_bf16(AL[ks], BH[0][ks], C0, 0, 0, 0);
                    C0 = __builtin_amdgcn_mfma_f32_16x16x32_bf16(AH[ks], BL[0][ks], C0, 0, 0, 0);
                }
            }
            #pragma unroll
            for (int r = 0; r < 4; ++r)
                preT[0][(tA * 16 + 4 * quad + r) * 20 + lrow] = C0[r];
            if (w7i < 6) {
                f32x4 C1 = {biasv[1], biasv[1], biasv[1], biasv[1]};
                #pragma unroll
                for (int ks = 0; ks < 4; ++ks) {
                    if (ks < KSRT) {
                        C1 = __builtin_amdgcn_mfma_f32_16x16x32_bf16(AH[ks], BH[1][ks], C1, 0, 0, 0);
                        C1 = __builtin_amdgcn_mfma_f32_16x16x32_bf16(AL[ks], BH[1][ks], C1, 0, 0, 0);
                        C1 = __builtin_amdgcn_mfma_f32_16x16x32_bf16(AH[ks], BL[1][ks], C1, 0, 0, 0);
                    }
                }
                #pragma unroll
                for (int r = 0; r < 4; ++r)
                    preT[0][(tB * 16 + 4 * quad + r) * 20 + lrow] = C1[r];
            }

            // G: EW -> own h plane + (B x-region | h_sh)
            {
                const f32x4 gt = *(const f32x4*)&preT[0][(tA * 16 + lrow) * 20 + 4 * quad];
                const float i_ = sigmoidf_(gt.x);
                const float f_ = sigmoidf_(gt.y);
                const float g_ = tanhf_(gt.z);
                const float o_ = sigmoidf_(gt.w);
                cc0 = f_ * cc0 + i_ * g_;
                const float hv = o_ * tanhf_(cc0);
                short hh, hl;
                bf16split(hv, hh, hl);
                Ahi[0][pa ^ 1][ah0] = hh;
                Alo[0][pa ^ 1][ah0] = hl;
                if (cls < 3) {
                    Ahi[1][pa ^ 1][bx0] = hh;
                    Alo[1][pa ^ 1][bx0] = hl;
                } else {
                    h_sh[pa ^ 1][lrow][j0] = hv;
                }
            }
            if (v1) {
                const f32x4 gt = *(const f32x4*)&preT[0][(tB * 16 + lrow) * 20 + 4 * quad];
                const float i_ = sigmoidf_(gt.x);
                const float f_ = sigmoidf_(gt.y);
                const float g_ = tanhf_(gt.z);
                const float o_ = sigmoidf_(gt.w);
                cc1 = f_ * cc1 + i_ * g_;
                const float hv = o_ * tanhf_(cc1);
                short hh, hl;
                bf16split(hv, hh, hl);
                Ahi[0][pa ^ 1][ah1] = hh;
                Alo[0][pa ^ 1][ah1] = hl;
                if (cls < 3) {
                    Ahi[1][pa ^ 1][bx1] = hh;
                    Alo[1][pa ^ 1][bx1] = hl;
                } else {
                    h_sh[pa ^ 1][lrow][j1] = hv;
                }
            }

            // C: stage x(t+1) from xUse (loaded one body earlier).
            // cls>0: payload is PACKED bf16 pairs -> 2-op unpack per value.
            if (is_ld && (i + 1) < TT) {
                if (cls == 0) {
                    short h_, l_;
                    bf16split(xUse.x, h_, l_);
                    Ahi[0][pa ^ 1][a_st] = h_; Alo[0][pa ^ 1][a_st] = l_;
                } else {
                    short h0,l0_,h1,l1_,h2,l2_,h3,l3_;
                    unpack_hl(xUse.x, h0, l0_); unpack_hl(xUse.y, h1, l1_);
                    unpack_hl(xUse.z, h2, l2_); unpack_hl(xUse.w, h3, l3_);
                    short4v vh = {h0,h1,h2,h3}, vl = {l0_,l1_,l2_,l3_};
                    *(short4v*)&Ahi[0][pa ^ 1][a_st] = vh;
                    *(short4v*)&Alo[0][pa ^ 1][a_st] = vl;
                }
            }
        } else if (bAct) {
            // ---- B-half: step t_b = i-1 ----------------------------------
            short8 AH[4], AL[4];
            #pragma unroll
            for (int ks = 0; ks < 4; ++ks) {
                AH[ks] = *(const short8*)&Ahi[1][pa][ks * 512 + lane * 8];
                AL[ks] = *(const short8*)&Alo[1][pa][ks * 512 + lane * 8];
            }
            f32x4 C0 = {biasv[0], biasv[0], biasv[0], biasv[0]};
            #pragma unroll
            for (int ks = 0; ks < 4; ++ks) {
                C0 = __builtin_amdgcn_mfma_f32_16x16x32_bf16(AH[ks], BH[0][ks], C0, 0, 0, 0);
                C0 = __builtin_amdgcn_mfma_f32_16x16x32_bf16(AL[ks], BH[0][ks], C0, 0, 0, 0);
                C0 = __builtin_amdgcn_mfma_f32_16x16x32_bf16(AH[ks], BL[0][ks], C0, 0, 0, 0);
            }
            #pragma unroll
            for (int r = 0; r < 4; ++r)
                preT[1][(tA * 16 + 4 * quad + r) * 20 + lrow] = C0[r];
            if (w7i < 6) {
                f32x4 C1 = {biasv[1], biasv[1], biasv[1], biasv[1]};
                #pragma unroll
                for (int ks = 0; ks < 4; ++ks) {
                    C1 = __builtin_amdgcn_mfma_f32_16x16x32_bf16(AH[ks], BH[1][ks], C1, 0, 0, 0);
                    C1 = __builtin_amdgcn_mfma_f32_16x16x32_bf16(AL[ks], BH[1][ks], C1, 0, 0, 0);
                    C1 = __builtin_amdgcn_mfma_f32_16x16x32_bf16(AH[ks], BL[1][ks], C1, 0, 0, 0);
                }
                #pragma unroll
                for (int r = 0; r < 4; ++r)
                    preT[1][(tB * 16 + 4 * quad + r) * 20 + lrow] = C1[r];
            }

            // EW -> own h plane + h_st (PACKED bf16 pair; store waves ship
            // the bits unchanged, consumer unpacks)
            {
                const f32x4 gt = *(const f32x4*)&preT[1][(tA * 16 + lrow) * 20 + 4 * quad];
                const float i_ = sigmoidf_(gt.x);
                const float f_ = sigmoidf_(gt.y);
                const float g_ = tanhf_(gt.z);
                const float o_ = sigmoidf_(gt.w);
                cc0 = f_ * cc0 + i_ * g_;
                const float hv = o_ * tanhf_(cc0);
                short hh, hl;
                bf16split(hv, hh, hl);
                Ahi[1][pa ^ 1][ah0] = hh;
                Alo[1][pa ^ 1][ah0] = hl;
                h_st[p2][tA * 64 + lane] = pack_hl(hh, hl);
            }
            if (v1) {
                const f32x4 gt = *(const f32x4*)&preT[1][(tB * 16 + lrow) * 20 + 4 * quad];
                const float i_ = sigmoidf_(gt.x);
                const float f_ = sigmoidf_(gt.y);
                const float g_ = tanhf_(gt.z);
                const float o_ = sigmoidf_(gt.w);
                cc1 = f_ * cc1 + i_ * g_;
                const float hv = o_ * tanhf_(cc1);
                short hh, hl;
                bf16split(hv, hh, hl);
                Ahi[1][pa ^ 1][ah1] = hh;
                Alo[1][pa ^ 1][ah1] = hl;
                h_st[p2][tB * 64 + lane] = pack_hl(hh, hl);
            }
        }

        // FC (class 3, B-half lanes): out(t = i-1) from h_sh[pa]
        if (cls == 3 && half && tloc < 112 && i >= 1) {
            const int s = tloc / 7;
            const int o = tloc - s * 7;
            const float* hr = h_sh[pa][s];
            float acc = bsh[o];
            #pragma unroll
            for (int k = 0; k < 52; k += 4) {
                const f32x4 hv4 = *(const f32x4*)&hr[k];
                const f32x4 wv4 = *(const f32x4*)&w7[o][k];
                acc = fmaf(hv4.x, wv4.x, acc);
                acc = fmaf(hv4.y, wv4.y, acc);
                acc = fmaf(hv4.z, wv4.z, acc);
                acc = fmaf(hv4.w, wv4.w, acc);
            }
            outp[((size_t)(b0 + s) * TT + (i - 1)) * 7 + o] = acc;
        }

        // H: producer wrap gate — before B enters ring block i>>3
        if (cls < 3 && (i & 7) == 0 && i >= RW * 8 && i < TT && pollH) {
            const int need = (i >> 3) - RW + 1;
            while (flag_ld(cons_poll) < need) __builtin_amdgcn_s_sleep(1);
        }

        WGBAR();   // lgkm-only; vm loads/stores stay in flight
    };

    // ---- iteration loop: unroll x2, alternating use/fill regs ------------
    for (int ii = 0; ii < TT; ii += 2) {
        body(ii,     xO, xE);    // even: stage from xO, load into xE
        body(ii + 1, xE, xO);    // odd:  stage from xE, load into xO
    }
    body(TT, xO, xE);            // trailing B-half drain iteration

    // B-half epilogue: h(511) is in h_st[1]; final WGBAR made it visible
    if (is_stw) {
        const int offp = ((511 >> 3) & (RW - 1)) * SLOT_BLK + (511 & 7) * SLOT_STEP;
        const float* hs = h_st[1];
        #pragma unroll
        for (int q = 0; q < 5; ++q) {
            if (q < st_ntt) {
                const int tt = st_t0 + q;
                ring_st(rout_g + offp + tt * 64 + lane, hs[tt * 64 + lane]);
            }
        }
    }
    if (cls < 3) {
        VMDRAIN();
        __syncthreads();
        if (tid == 704)
            flag_st(flag_out, 64);
    }
}

// ======================= fallback path (R4, per-layer) ======================

template<int DIN>
__global__ __launch_bounds__(448)
void lstm_fb(const float* xin, float* hout,
             const float* __restrict__ Wih, const float* __restrict__ Whh,
             const float* __restrict__ bihp, const float* __restrict__ bhhp)
{
    constexpr int XO = 52;
    constexpr int KTOT = XO + DIN;
    constexpr int KSTEPS = (KTOT + 31) / 32;
    __shared__ short Ahi[2][KSTEPS * 512];
    __shared__ short Alo[2][KSTEPS * 512];
    __shared__ float preT[13 * 64];

    const int tid = threadIdx.x, wave = tid >> 6, lane = tid & 63;
    const int quad = lane >> 4, lrow = lane & 15;
    const int b0 = blockIdx.x * 4;
    const int ntiles = (wave < 6) ? 2 : 1;
    const int tileA = (wave < 6) ? wave : 12;
    const int tileB = wave + 6;

    short8 BH[2][KSTEPS], BL[2][KSTEPS];
    float biasv[2];
    #pragma unroll
    for (int ti = 0; ti < 2; ++ti) {
        const int nt = ti ? tileB : tileA;
        const bool valid = (ti < ntiles);
        const int np = nt * 16 + lrow, j = np >> 2, g = np & 3;
        biasv[ti] = (valid && j < HH) ? (bihp[g*HH+j] + bhhp[g*HH+j]) : 0.0f;
        #pragma unroll
        for (int ks = 0; ks < KSTEPS; ++ks)
            #pragma unroll
            for (int jj = 0; jj < 8; ++jj) {
                const int k = ks * 32 + quad * 8 + jj;
                float wv = 0.0f;
                if (valid && j < HH) {
                    const int r = g * HH + j;
                    if (k < HH) wv = Whh[r * HH + k];
                    else if (k >= XO && k < KTOT) wv = Wih[r * DIN + (k - XO)];
                }
                short h_, l_; bf16split(wv, h_, l_);
                BH[ti][ks][jj] = h_; BL[ti][ks][jj] = l_;
            }
    }

    const int ec = lane & 15, ew_jj = ec >> 2, ew_m = ec & 3, ew_ti = lane >> 4;
    const bool is_ew = (lane < 32) && (ew_ti < ntiles);
    const int ew_nt = ew_ti ? tileB : tileA;
    const int ew_j = 4 * ew_nt + ew_jj;
    const bool ew_ok = is_ew && (ew_j < HH);
    const int pa0 = (ew_nt*16 + 4*ew_jj + 0)*4 + ew_m;
    const int pa1 = (ew_nt*16 + 4*ew_jj + 1)*4 + ew_m;
    const int pa2 = (ew_nt*16 + 4*ew_jj + 2)*4 + ew_m;
    const int pa3 = (ew_nt*16 + 4*ew_jj + 3)*4 + ew_m;
    const int ew_ah = addr2B(ew_m, ew_j);
    float cc = 0.0f;

    const int lx = tid;
    const bool is_loader = (lx < 4 * DIN);
    const int ld_m = is_loader ? (lx & 3) : 0, ld_k = is_loader ? (lx >> 2) : 0;
    const int xaddr = addr2B(ld_m, XO + ld_k);
    const size_t xbase = ((size_t)(b0 + ld_m) * TT) * DIN + ld_k;
    float* houtp = hout + ((size_t)(b0 + ew_m) * TT) * HH + (ew_ok ? ew_j : 0);

    for (int i = tid; i < KSTEPS * 512; i += 448) {
        ((unsigned*)Ahi)[i] = 0u; ((unsigned*)Alo)[i] = 0u;
    }
    __syncthreads();
    if (is_loader) {
        short h_, l_; bf16split(xin[xbase], h_, l_);
        Ahi[0][xaddr] = h_; Alo[0][xaddr] = l_;
    }
    __syncthreads();

    for (int t = 0; t < TT; ++t) {
        const int p = t & 1;
        float xnext = 0.0f;
        if (is_loader && (t + 1 < TT)) xnext = xin[xbase + (size_t)(t+1) * DIN];

        short8 AH[KSTEPS], AL[KSTEPS];
        #pragma unroll
        for (int ks = 0; ks < KSTEPS; ++ks) {
            AH[ks] = *(const short8*)&Ahi[p][ks * 512 + lane * 8];
            AL[ks] = *(const short8*)&Alo[p][ks * 512 + lane * 8];
        }
        #pragma unroll
        for (int ti = 0; ti < 2; ++ti) {
            f32x4 C = {biasv[ti], biasv[ti], biasv[ti], biasv[ti]};
            #pragma unroll
            for (int ks = 0; ks < KSTEPS; ++ks) {
                C = __builtin_amdgcn_mfma_f32_16x16x32_bf16(AH[ks], BH[ti][ks], C, 0, 0, 0);
                C = __builtin_amdgcn_mfma_f32_16x16x32_bf16(AL[ks], BH[ti][ks], C, 0, 0, 0);
                C = __builtin_amdgcn_mfma_f32_16x16x32_bf16(AH[ks], BL[ti][ks], C, 0, 0, 0);
            }
            if (ti < ntiles && lane < 16) {
                const int nt = ti ? tileB : tileA;
                *(f32x4*)&preT[(nt * 16 + lrow) * 4] = C;
            }
        }
        if (is_ew) {
            const float i_ = sigmoidf_(preT[pa0]);
            const float f_ = sigmoidf_(preT[pa1]);
            const float g_ = tanhf_(preT[pa2]);
            const float o_ = sigmoidf_(preT[pa3]);
            cc = f_ * cc + i_ * g_;
            const float hv = o_ * tanhf_(cc);
            if (ew_ok) {
                short hh, hl; bf16split(hv, hh, hl);
                Ahi[p ^ 1][ew_ah] = hh; Alo[p ^ 1][ew_ah] = hl;
                houtp[(size_t)t * HH] = hv;
            }
        }
        if (is_loader && (t + 1 < TT)) {
            short h_, l_; bf16split(xnext, h_, l_);
            Ahi[p ^ 1][xaddr] = h_; Alo[p ^ 1][xaddr] = l_;
        }
        __syncthreads();
    }
}

__global__ __launch_bounds__(256)
void fc_fb(const float* __restrict__ hbuf, const float* __restrict__ fcw,
           const float* __restrict__ fcb, float* __restrict__ outp)
{
    constexpr int HP = 52;
    __shared__ float w[7][HP];
    __shared__ float bsh[8];
    const int tid = threadIdx.x;
    for (int i = tid; i < 7 * HP; i += 256) {
        const int o = i / HP, k = i - o * HP;
        w[o][k] = (k < HH) ? fcw[o * HH + k] : 0.0f;
    }
    if (tid < 7) bsh[tid] = fcb[tid];
    __syncthreads();
    const size_t i = (size_t)blockIdx.x * 256 + tid;
    float acc[7];
    #pragma unroll
    for (int j = 0; j < 7; ++j) acc[j] = bsh[j];
    const float* hp = hbuf + i * HH;
    #pragma unroll
    for (int k = 0; k < HH; ++k) {
        const float hv = hp[k];
        #pragma unroll
        for (int j = 0; j < 7; ++j) acc[j] = fmaf(hv, w[j][k], acc[j]);
    }
    #pragma unroll
    for (int j = 0; j < 7; ++j) outp[i * 7 + j] = acc[j];
}

extern "C" void kernel_launch(void* const* d_in, const int* in_sizes, int n_in,
                              void* d_out, int out_size, void* d_ws, size_t ws_size,
                              hipStream_t stream)
{
    const float* x    = (const float*)d_in[0];
    const float* Wih0 = (const float*)d_in[1];
    const float* Wihr = (const float*)d_in[2];
    const float* Whh  = (const float*)d_in[3];
    const float* bih  = (const float*)d_in[4];
    const float* bhh  = (const float*)d_in[5];
    const float* fcw  = (const float*)d_in[6];
    const float* fcb  = (const float*)d_in[7];
    float* outp = (float*)d_out;

    if (ws_size >= WS_NEEDED) {
        float* ring  = (float*)d_ws;
        int*   flags = (int*)((char*)d_ws + RING_FLOATS * 4);
        zero_flags<<<(int)((FLAG_INTS + 255) / 256), 256, 0, stream>>>(
            flags, (int)FLAG_INTS);
        lstm_pair<<<256, 896, 0, stream>>>(x, ring, flags, Wih0, Wihr,
                                           Whh, bih, bhh, fcw, fcb, outp);
    } else {
        float* hbuf = (float*)d_ws;   // [B,T,49]
        lstm_fb<7><<<BB / 4, 448, 0, stream>>>(x, hbuf, Wih0, Whh, bih, bhh);
        for (int l = 1; l < 7; ++l) {
            lstm_fb<49><<<BB / 4, 448, 0, stream>>>(
                hbuf, hbuf,
                Wihr + (size_t)(l - 1) * GG * HH,
                Whh  + (size_t)l * GG * HH,
                bih  + (size_t)l * GG,
                bhh  + (size_t)l * GG);
        }
        fc_fb<<<(BB * TT) / 256, 256, 0, stream>>>(hbuf, fcw, fcb, outp);
    }
}